// Round 8
// baseline (138.329 us; speedup 1.0000x reference)
//
#include <hip/hip_runtime.h>
#include <math.h>

// ---------------------------------------------------------------------------
// EntRNN R8: two-kernel shape (R6, best so far). GEMM restructured:
//  - W reg-direct from L2 (k-major repacked -> coalesced b128 loads), no LDS,
//    NO barriers in K-loop (compiler pipelines across kk freely).
//  - A staged once to LDS f16 (16 KiB, xor-swizzled), one barrier total.
//  - 32-row blocks (1024 blocks), LDS 32 KiB, acc 64 VGPR -> ~3 blocks/CU.
// scan_final: 64-row blocks fold 32-granular summaries (unrolled), replay.
// B=8, T=4096, D=256.
// ---------------------------------------------------------------------------

typedef _Float16 f16x8 __attribute__((ext_vector_type(8)));
typedef float f32x4 __attribute__((ext_vector_type(4)));
typedef float f32x16 __attribute__((ext_vector_type(16)));

constexpr int B_ = 8, T_ = 4096, D_ = 256, K_ = 256;
constexpr int M_ = B_ * T_;          // 32768 rows
constexpr int GROWS = 32;            // gemm block rows (= summary granularity)
constexpr int NGB = M_ / GROWS;      // 1024 gemm blocks
constexpr int CHUNK = 64;            // scan_final rows per block
constexpr int NCH = T_ / CHUNK;      // 64

struct alignas(4) XF { _Float16 x, f; };

__device__ __forceinline__ float fexp2(float a) { return __builtin_amdgcn_exp2f(a); }
__device__ __forceinline__ float frcp(float a) { return __builtin_amdgcn_rcpf(a); }
constexpr float L2E = 1.4426950408889634f;

__device__ __forceinline__ float fast_sigmoid(float z) {
  return frcp(1.f + fexp2(-z * L2E));
}
__device__ __forceinline__ float fast_tanh(float z) {
  const float t = fexp2(-2.f * L2E * fabsf(z));
  return copysignf((1.f - t) * frcp(1.f + t), z);
}

// ---- K0: repack W fp32 -> f16, k-major chunks: g = kk*2048+(mat*4+kc)*256+n
__global__ __launch_bounds__(256) void wconv(const float* __restrict__ Win,
                                             const float* __restrict__ Wf,
                                             _Float16* __restrict__ Wh2) {
  const int t = blockIdx.x * 256 + threadIdx.x;
  const int n = t & 255;
  const int kc = (t >> 8) & 3;
  const int mat = (t >> 10) & 1;
  const int kk = t >> 11;
  const float* s = (mat ? Wf : Win) + (size_t)n * K_ + kk * 32 + kc * 8;
  f32x4 a = *(const f32x4*)s;
  f32x4 b = *(const f32x4*)(s + 4);
  f16x8 o;
  o[0] = (_Float16)a[0]; o[1] = (_Float16)a[1];
  o[2] = (_Float16)a[2]; o[3] = (_Float16)a[3];
  o[4] = (_Float16)b[0]; o[5] = (_Float16)b[1];
  o[6] = (_Float16)b[2]; o[7] = (_Float16)b[3];
  *(f16x8*)(Wh2 + (size_t)t * 8) = o;
}

// ---- K1: 32-row GEMM (W reg-direct, barrier-free K-loop) + act + scan -----
// 1024 blocks x 256 thr. Wave w covers cols [w*64, w*64+64) of both mats;
// all 32 rows. acc[mat][nt] = 4 x 16 = 64 VGPR.
// LDS 32 KiB: A [m(32)][swz(32)] 16B chunks in K-loop; XF[32][256] after.
__global__ __launch_bounds__(256, 3) void gemm32(
    const float* __restrict__ A, const _Float16* __restrict__ Wh2,
    const float* __restrict__ bin, const float* __restrict__ bfv,
    const float* __restrict__ mask, XF* __restrict__ xf,
    float* __restrict__ Ap, float* __restrict__ Hp) {
  __shared__ __align__(16) char smem[32768];
  char* ldsA = smem;   // 16 KiB during K-loop

  const int tid = threadIdx.x;
  const int w = tid >> 6, lane = tid & 63;
  const int nl = lane & 31, kh = lane >> 5;
  const int g = blockIdx.x;
  const int row0 = g * GROWS;

  f32x16 acc[2][2];
#pragma unroll
  for (int mat = 0; mat < 2; ++mat)
#pragma unroll
    for (int nt = 0; nt < 2; ++nt) acc[mat][nt] = (f32x16)(0.f);

  // ---- stage A (32 rows x 256 k) fp32->f16, xor-swizzled; ONE barrier ----
  {
    const int am = tid >> 3;               // row 0..31
    const int kb = (tid & 7) * 4;          // base chunk (8 f16 per chunk)
    const float* agp = A + (size_t)(row0 + am) * K_ + kb * 8;
#pragma unroll
    for (int j = 0; j < 4; ++j) {
      const int kcg = kb + j;
      f32x4 lo = *(const f32x4*)(agp + j * 8);
      f32x4 hi = *(const f32x4*)(agp + j * 8 + 4);
      f16x8 t;
      t[0] = (_Float16)lo[0]; t[1] = (_Float16)lo[1];
      t[2] = (_Float16)lo[2]; t[3] = (_Float16)lo[3];
      t[4] = (_Float16)hi[0]; t[5] = (_Float16)hi[1];
      t[6] = (_Float16)hi[2]; t[7] = (_Float16)hi[3];
      *(f16x8*)(ldsA + am * 512 + ((kcg ^ am) << 4)) = t;
    }
  }
  __syncthreads();

  // ---- K-loop: NO barriers. B-frags stream from L2 (coalesced, k-major). --
#pragma unroll 2
  for (int kk = 0; kk < 8; ++kk) {
    f16x8 afr[2];
#pragma unroll
    for (int i2 = 0; i2 < 2; ++i2) {
      const int kcg = kk * 4 + i2 * 2 + kh;
      afr[i2] = *(const f16x8*)(ldsA + nl * 512 + ((kcg ^ nl) << 4));
    }
#pragma unroll
    for (int mat = 0; mat < 2; ++mat)
#pragma unroll
      for (int nt = 0; nt < 2; ++nt) {
        const int n = w * 64 + nt * 32 + nl;
#pragma unroll
        for (int i2 = 0; i2 < 2; ++i2) {
          const int kc = i2 * 2 + kh;
          f16x8 bfr = *(const f16x8*)(Wh2 + (size_t)kk * 16384 +
                                      (size_t)((mat * 4 + kc) * 256 + n) * 8);
          acc[mat][nt] = __builtin_amdgcn_mfma_f32_32x32x16_f16(
              afr[i2], bfr, acc[mat][nt], 0, 0, 0);
        }
      }
  }
  __syncthreads();   // A-tile reads done; smem becomes XF[32][256]

  // ---- epilogue: bias + mask + activations -> XF (LDS + global) ----
  float bx[2], bf[2];
#pragma unroll
  for (int nt = 0; nt < 2; ++nt) {
    const int col = w * 64 + nt * 32 + nl;
    bx[nt] = bin[col];
    bf[nt] = bfv[col];
  }
  float madd[16];
  int rowl[16];
#pragma unroll
  for (int reg = 0; reg < 16; ++reg) {
    const int rl = (reg & 3) + 8 * (reg >> 2) + 4 * kh;   // 0..31
    rowl[reg] = rl;
    madd[reg] = 10000.f * mask[row0 + rl];
  }
#pragma unroll
  for (int nt = 0; nt < 2; ++nt) {
    const int col = w * 64 + nt * 32 + nl;
#pragma unroll
    for (int reg = 0; reg < 16; ++reg) {
      const float zx = acc[0][nt][reg] + bx[nt];
      const float zf = acc[1][nt][reg] + bf[nt] + madd[reg];
      XF v;
      v.x = (_Float16)fast_tanh(zx);
      v.f = (_Float16)fast_sigmoid(zf);
      *(XF*)(smem + ((size_t)rowl[reg] * D_ + col) * 4) = v;
      xf[((size_t)row0 + rowl[reg]) * D_ + col] = v;
    }
  }
  __syncthreads();

  // ---- local scan over 32 t from LDS -> summary ----
  const int d = tid;
  float Aa = 1.f, h = 0.f;
#pragma unroll 8
  for (int t = 0; t < GROWS; ++t) {
    const XF v = *(const XF*)(smem + ((size_t)t * D_ + d) * 4);
    const float f = (float)v.f;
    const float a = 1.f - f;
    h = f * (float)v.x + a * h;
    Aa *= a;
  }
  Ap[(size_t)g * D_ + d] = Aa;
  Hp[(size_t)g * D_ + d] = h;
}

// ---- K2: fold 32-granular predecessor summaries + replay 64 rows ----------
__global__ __launch_bounds__(256) void scan_final(const XF* __restrict__ xf,
                                                  const float* __restrict__ Ap,
                                                  const float* __restrict__ Hp,
                                                  float* __restrict__ out) {
  const int g = blockIdx.x;           // 512 blocks of 64 rows
  const int b = g >> 6, c = g & 63;
  const int d = threadIdx.x;
  const size_t s0 = ((size_t)b << 7) * D_ + d;   // seq b's first 32-summary
  const int nj = 2 * c;                          // predecessors (32-granular)
  float h = 0.f;
#pragma unroll 4
  for (int j = 0; j < nj; ++j)
    h = Hp[s0 + (size_t)j * D_] + Ap[s0 + (size_t)j * D_] * h;

  const size_t base = (size_t)g * CHUNK * D_ + d;
#pragma unroll 8
  for (int t = 0; t < CHUNK; ++t) {
    const XF v = xf[base + (size_t)t * D_];
    const float f = (float)v.f;
    h = f * (float)v.x + (1.f - f) * h;
    out[base + (size_t)t * D_] = h;
  }
}

// ---------------------------------------------------------------------------
extern "C" void kernel_launch(void* const* d_in, const int* in_sizes, int n_in,
                              void* d_out, int out_size, void* d_ws, size_t ws_size,
                              hipStream_t stream) {
  const float* inputs = (const float*)d_in[0];
  const float* mask   = (const float*)d_in[1];
  const float* W_in   = (const float*)d_in[2];
  const float* b_in   = (const float*)d_in[3];
  const float* W_f    = (const float*)d_in[4];
  const float* b_f    = (const float*)d_in[5];
  float* out = (float*)d_out;
  char* ws = (char*)d_ws;

  constexpr size_t XFSZ = (size_t)M_ * D_ * sizeof(XF);            // 32 MiB
  constexpr size_t WSZ  = (size_t)2 * 256 * 256 * 2;               // 256 KiB
  constexpr size_t SUM  = (size_t)NGB * D_ * sizeof(float);        // 1 MiB

  XF* xf = (XF*)ws;
  _Float16* Wh2 = (_Float16*)(ws + XFSZ);
  float* Ap = (float*)(ws + XFSZ + WSZ);
  float* Hp = Ap + SUM / sizeof(float);

  wconv<<<64, 256, 0, stream>>>(W_in, W_f, Wh2);
  gemm32<<<NGB, 256, 0, stream>>>(inputs, Wh2, b_in, b_f, mask, xf, Ap, Hp);
  scan_final<<<512, 256, 0, stream>>>(xf, Ap, Hp, out);
}

// Round 10
// 128.032 us; speedup vs baseline: 1.0804x; 1.0804x over previous
//
#include <hip/hip_runtime.h>
#include <math.h>

// ---------------------------------------------------------------------------
// EntRNN R10: R9 with the W-prefetch stride bug fixed (kk2 stride is 8192
// elements = 1024 chunks, was 4096). Structure: R6's K-loop with K-step 16
// (48 KiB LDS -> 3 blocks/CU); epilogue scans in two 32-row phases and
// stores (h_local, P) packed f16x2 via coalesced b128; scan_mid computes
// chunk carries; final_k is pure elementwise streaming. B=8, T=4096, D=256.
// ---------------------------------------------------------------------------

typedef _Float16 f16x8 __attribute__((ext_vector_type(8)));
typedef float f32x4 __attribute__((ext_vector_type(4)));
typedef float f32x16 __attribute__((ext_vector_type(16)));
typedef unsigned int u32x4 __attribute__((ext_vector_type(4)));

constexpr int B_ = 8, T_ = 4096, D_ = 256, K_ = 256;
constexpr int M_ = B_ * T_;          // 32768 rows
constexpr int CHUNK = 64;            // rows per gemm block == scan chunk
constexpr int NCH = T_ / CHUNK;      // 64 chunks per sequence
constexpr int NBLK = M_ / CHUNK;     // 512 gemm blocks
constexpr int SLICE_EL = 8192;       // W slice stride: 1024 chunks * 8 f16

struct alignas(4) XF { _Float16 x, f; };
struct alignas(4) HP2 { _Float16 h, p; };
union UHP { unsigned int u; HP2 hp; XF xf; };

__device__ __forceinline__ float fexp2(float a) { return __builtin_amdgcn_exp2f(a); }
__device__ __forceinline__ float frcp(float a) { return __builtin_amdgcn_rcpf(a); }
constexpr float L2E = 1.4426950408889634f;

__device__ __forceinline__ float fast_sigmoid(float z) {
  return frcp(1.f + fexp2(-z * L2E));
}
__device__ __forceinline__ float fast_tanh(float z) {
  const float t = fexp2(-2.f * L2E * fabsf(z));
  return copysignf((1.f - t) * frcp(1.f + t), z);
}

// ---- K0: repack W fp32 -> f16. Chunk id t = kk2*1024 + (mat*2+kc)*256 + n,
// chunk = W[n][kk2*16 + kc*8 .. +8). 16384 chunks of 8 f16.
__global__ __launch_bounds__(256) void wconv(const float* __restrict__ Win,
                                             const float* __restrict__ Wf,
                                             _Float16* __restrict__ Wh2) {
  const int t = blockIdx.x * 256 + threadIdx.x;
  const int n = t & 255;
  const int kc = (t >> 8) & 1;
  const int mat = (t >> 9) & 1;
  const int kk2 = t >> 10;
  const float* s = (mat ? Wf : Win) + (size_t)n * K_ + kk2 * 16 + kc * 8;
  f32x4 a = *(const f32x4*)s;
  f32x4 b = *(const f32x4*)(s + 4);
  f16x8 o;
  o[0] = (_Float16)a[0]; o[1] = (_Float16)a[1];
  o[2] = (_Float16)a[2]; o[3] = (_Float16)a[3];
  o[4] = (_Float16)b[0]; o[5] = (_Float16)b[1];
  o[6] = (_Float16)b[2]; o[7] = (_Float16)b[3];
  *(f16x8*)(Wh2 + (size_t)t * 8) = o;
}

// ---- K1: GEMM (R6 K-loop, K-step 16) + activations + local scan -> HP -----
// 512 blocks x 256 thr, 48 KiB LDS -> 3 blocks/CU. 4 waves: mw=w>>1 (32-row
// half), nw=w&1 (128-col half).
__global__ __launch_bounds__(256, 3) void gemm_hp(
    const float* __restrict__ A, const _Float16* __restrict__ Wh2,
    const float* __restrict__ bin, const float* __restrict__ bfv,
    const float* __restrict__ mask, unsigned int* __restrict__ HPout,
    float* __restrict__ Ap, float* __restrict__ Hp) {
  __shared__ __align__(16) char smem[49152];
  char* ldsA = smem;            // 32 KiB: [m(64)][swz(32)] 16B, swz = kcg^(m&31)
  char* ldsW = smem + 32768;    // 16 KiB slice: [(mat*2+kc)*256 + n] 16B

  const int tid = threadIdx.x;
  const int w = tid >> 6, lane = tid & 63;
  const int mw = w >> 1, nw = w & 1;
  const int nl = lane & 31, kh = lane >> 5;
  const int ml = mw * 32 + nl;
  const int g = blockIdx.x;
  const int row0 = g * CHUNK;

  f32x16 acc[2][4];
#pragma unroll
  for (int mat = 0; mat < 2; ++mat)
#pragma unroll
    for (int nt = 0; nt < 4; ++nt) acc[mat][nt] = (f32x16)(0.f);

  // ---- stage ALL of A (64 x 256) fp32->f16, xor-swizzled (as R6) ----
  {
    const int am = tid >> 2;
    const int ak4 = (tid & 3) * 8;
    const float* agp = A + (size_t)(row0 + am) * K_ + ak4 * 8;
#pragma unroll
    for (int j = 0; j < 8; ++j) {
      const int kcg = ak4 + j;
      f32x4 lo = *(const f32x4*)(agp + j * 8);
      f32x4 hi = *(const f32x4*)(agp + j * 8 + 4);
      f16x8 t;
      t[0] = (_Float16)lo[0]; t[1] = (_Float16)lo[1];
      t[2] = (_Float16)lo[2]; t[3] = (_Float16)lo[3];
      t[4] = (_Float16)hi[0]; t[5] = (_Float16)hi[1];
      t[6] = (_Float16)hi[2]; t[7] = (_Float16)hi[3];
      *(f16x8*)(ldsA + am * 512 + ((kcg ^ (am & 31)) << 4)) = t;
    }
  }
  __syncthreads();

  // ---- prologue: W slice kk2=0 into regs (4 x b128) ----
  f16x8 wreg[4];
#pragma unroll
  for (int j = 0; j < 4; ++j)
    wreg[j] = *(const f16x8*)(Wh2 + (size_t)(j * 256 + tid) * 8);

  // ---- K-loop: 16 slices of K=16 (R6 pattern) ----
  for (int kk2 = 0; kk2 < 16; ++kk2) {
#pragma unroll
    for (int j = 0; j < 4; ++j)
      *(f16x8*)(ldsW + (size_t)(j * 256 + tid) * 16) = wreg[j];
    if (kk2 < 15) {
#pragma unroll
      for (int j = 0; j < 4; ++j)
        wreg[j] = *(const f16x8*)(Wh2 + (size_t)(kk2 + 1) * SLICE_EL +
                                  (size_t)(j * 256 + tid) * 8);
    }
    __syncthreads();
    f16x8 afr;
    {
      const int kcg = kk2 * 2 + kh;
      afr = *(const f16x8*)(ldsA + ml * 512 + ((kcg ^ (ml & 31)) << 4));
    }
#pragma unroll
    for (int mat = 0; mat < 2; ++mat)
#pragma unroll
      for (int nt = 0; nt < 4; ++nt) {
        const int n = nw * 128 + nt * 32 + nl;
        f16x8 bfr = *(const f16x8*)(ldsW + (size_t)((mat * 2 + kh) * 256 + n) * 16);
        acc[mat][nt] = __builtin_amdgcn_mfma_f32_32x32x16_f16(
            afr, bfr, acc[mat][nt], 0, 0, 0);
      }
    __syncthreads();
  }

  // ---- epilogue: two 32-row phases in 32 KiB LDS ----
  float bx[4], bf[4];
#pragma unroll
  for (int nt = 0; nt < 4; ++nt) {
    const int col = nw * 128 + nt * 32 + nl;
    bx[nt] = bin[col];
    bf[nt] = bfv[col];
  }
  float madd[16];
#pragma unroll
  for (int reg = 0; reg < 16; ++reg) {
    const int rl = mw * 32 + (reg & 3) + 8 * (reg >> 2) + 4 * kh;
    madd[reg] = 10000.f * mask[row0 + rl];
  }

  const int d = tid;
  float hrun = 0.f, Prun = 1.f;
#pragma unroll
  for (int p = 0; p < 2; ++p) {
    if (mw == p) {  // waves holding rows [p*32, p*32+32) unpack into LDS
#pragma unroll
      for (int nt = 0; nt < 4; ++nt) {
        const int col = nw * 128 + nt * 32 + nl;
#pragma unroll
        for (int reg = 0; reg < 16; ++reg) {
          const int rloc = (reg & 3) + 8 * (reg >> 2) + 4 * kh;  // 0..31
          const float zx = acc[0][nt][reg] + bx[nt];
          const float zf = acc[1][nt][reg] + bf[nt] + madd[reg];
          XF v;
          v.x = (_Float16)fast_tanh(zx);
          v.f = (_Float16)fast_sigmoid(zf);
          *(XF*)(smem + ((size_t)rloc * D_ + col) * 4) = v;
        }
      }
    }
    __syncthreads();
    // scan 32 timesteps, write back packed (h_local, P) in place
#pragma unroll 8
    for (int t = 0; t < 32; ++t) {
      char* slot = smem + ((size_t)t * D_ + d) * 4;
      const XF v = *(const XF*)slot;
      const float f = (float)v.f;
      const float a = 1.f - f;
      hrun = f * (float)v.x + a * hrun;
      Prun *= a;
      HP2 o;
      o.h = (_Float16)hrun;
      o.p = (_Float16)Prun;
      *(HP2*)slot = o;
    }
    __syncthreads();
    // bulk-coalesced b128 store of this 32-row phase (32 KiB)
#pragma unroll
    for (int j = 0; j < 8; ++j) {
      const int c = j * 256 + tid;            // 16B chunk id in [0,2048)
      u32x4 vv = *(const u32x4*)(smem + (size_t)c * 16);
      *(u32x4*)(HPout + (size_t)g * 16384 + (size_t)p * 8192 + (size_t)c * 4) = vv;
    }
    __syncthreads();
  }

  Ap[(size_t)g * D_ + d] = Prun;
  Hp[(size_t)g * D_ + d] = hrun;
}

// ---- K2: chunk carries. 8 blocks (one per sequence) x 256 thr -------------
__global__ __launch_bounds__(256) void scan_mid(const float* __restrict__ Ap,
                                                const float* __restrict__ Hp,
                                                float* __restrict__ hs) {
  const int b = blockIdx.x, d = threadIdx.x;
  float h = 0.f;
#pragma unroll 8
  for (int c = 0; c < NCH; ++c) {
    const size_t i = ((size_t)(b * NCH + c)) * D_ + d;
    hs[i] = h;                         // carry INTO chunk c
    h = Hp[i] + Ap[i] * h;
  }
}

// ---- K3: elementwise h = h_local + P * h_start, pure streaming ------------
__global__ __launch_bounds__(256) void final_k(const unsigned int* __restrict__ HP,
                                               const float* __restrict__ hs,
                                               float* __restrict__ out) {
  const int g = blockIdx.x;
  const int lane = threadIdx.x & 63, wv = threadIdx.x >> 6;
  const int d0 = lane * 4;
  const f32x4 h0 = *(const f32x4*)(hs + (size_t)g * D_ + d0);
#pragma unroll 4
  for (int tt = 0; tt < 16; ++tt) {
    const int t = wv * 16 + tt;
    const size_t idx = ((size_t)g * CHUNK + t) * D_ + d0;
    u32x4 u = *(const u32x4*)(HP + idx);
    f32x4 o;
#pragma unroll
    for (int i = 0; i < 4; ++i) {
      UHP q; q.u = u[i];
      o[i] = (float)q.hp.h + (float)q.hp.p * h0[i];
    }
    *(f32x4*)(out + idx) = o;
  }
}

// ---------------------------------------------------------------------------
extern "C" void kernel_launch(void* const* d_in, const int* in_sizes, int n_in,
                              void* d_out, int out_size, void* d_ws, size_t ws_size,
                              hipStream_t stream) {
  const float* inputs = (const float*)d_in[0];
  const float* mask   = (const float*)d_in[1];
  const float* W_in   = (const float*)d_in[2];
  const float* b_in   = (const float*)d_in[3];
  const float* W_f    = (const float*)d_in[4];
  const float* b_f    = (const float*)d_in[5];
  float* out = (float*)d_out;
  char* ws = (char*)d_ws;

  constexpr size_t HPSZ = (size_t)M_ * D_ * 4;                    // 32 MiB
  constexpr size_t WSZ  = (size_t)2 * 256 * 256 * 2;              // 256 KiB
  constexpr size_t SUM  = (size_t)NBLK * D_ * sizeof(float);      // 512 KiB

  unsigned int* HPb = (unsigned int*)ws;
  _Float16* Wh2 = (_Float16*)(ws + HPSZ);
  float* Ap = (float*)(ws + HPSZ + WSZ);
  float* Hp = (float*)(ws + HPSZ + WSZ + SUM);
  float* hs = (float*)(ws + HPSZ + WSZ + 2 * SUM);

  wconv<<<64, 256, 0, stream>>>(W_in, W_f, Wh2);
  gemm_hp<<<NBLK, 256, 0, stream>>>(inputs, Wh2, b_in, b_f, mask, HPb, Ap, Hp);
  scan_mid<<<B_, 256, 0, stream>>>(Ap, Hp, hs);
  final_k<<<NBLK, 256, 0, stream>>>(HPb, hs, out);
}